// Round 9
// baseline (594.831 us; speedup 1.0000x reference)
//
#include <hip/hip_runtime.h>
#include <math.h>

// AttentionPool: scores = einsum("btd,d->bt"), masked softmax over T,
// pooled = einsum("bt,btd->bd").  B=16, T=4096, D=1024, f32.
//
// Fused single-pass online-softmax pooling, SOFTWARE-PIPELINED:
// round-7 profile showed 555 GB/s (7% peak), VALUBusy 2%, VGPR=36 -> the
// compiler did no prefetching; every token serialized full memory latency.
// Now: 2-token groups, double-buffered in named register arrays (8 x f32x4
// + int2 mask per buffer); issue group g+1's loads before computing group g.
// Butterfly reduces of the 2 tokens interleaved for ILP; dot split into 2
// partial chains. Plain loads (no nt) — harness restore leaves H L3-resident.

typedef float f32x4 __attribute__((ext_vector_type(4)));

__global__ __launch_bounds__(256) void ap_fused(
    const float* __restrict__ hs, const int* __restrict__ mask,
    const float* __restrict__ ctx,
    float* __restrict__ accs, float* __restrict__ ms, float* __restrict__ ls,
    int* __restrict__ counters, float* __restrict__ out,
    int T, int blocksPerB, int tokensPerWave)
{
    const int D = 1024;            // layout assumption: D == 1024 (4*64*4)
    int bi    = blockIdx.x;
    int b     = bi / blocksPerB;
    int chunk = bi - b * blocksPerB;
    int wave  = threadIdx.x >> 6;
    int lane  = threadIdx.x & 63;
    int tid   = threadIdx.x;

    int t0 = chunk * (tokensPerWave * 4) + wave * tokensPerWave;

    const f32x4* ctx4 = (const f32x4*)ctx;
    f32x4 c0 = ctx4[0 * 64 + lane];
    f32x4 c1 = ctx4[1 * 64 + lane];
    f32x4 c2 = ctx4[2 * 64 + lane];
    f32x4 c3 = ctx4[3 * 64 + lane];

    f32x4 a0 = {0.f,0.f,0.f,0.f}, a1 = {0.f,0.f,0.f,0.f};
    f32x4 a2 = {0.f,0.f,0.f,0.f}, a3 = {0.f,0.f,0.f,0.f};
    float m = -INFINITY, l = 0.0f;

    const f32x4* hp = (const f32x4*)hs + ((size_t)b * T + t0) * (D / 4);
    const int*   mp = mask + (size_t)b * T + t0;

    // ---- double-buffered 2-token groups (tokensPerWave is even: T/(4*bpB)) ----
    f32x4 hA[2][4], hB[2][4];      // [token-in-group][j] — all indices unrolled
    int2  mA, mB;
    int NG = tokensPerWave >> 1;

    auto loadG = [&](f32x4 (&h)[2][4], int2& mk, int gi) {
        const f32x4* r0 = hp + (size_t)(2 * gi    ) * (D / 4);
        const f32x4* r1 = hp + (size_t)(2 * gi + 1) * (D / 4);
        #pragma unroll
        for (int j = 0; j < 4; ++j) h[0][j] = r0[j * 64 + lane];
        #pragma unroll
        for (int j = 0; j < 4; ++j) h[1][j] = r1[j * 64 + lane];
        mk = *(const int2*)(mp + 2 * gi);
    };

    auto computeG = [&](f32x4 (&h)[2][4], int2 mk) {
        float p0 = 0.f, q0 = 0.f, p1 = 0.f, q1 = 0.f;
        #pragma unroll
        for (int e = 0; e < 4; ++e) {
            p0 = fmaf(h[0][0][e], c0[e], p0);
            q0 = fmaf(h[0][1][e], c1[e], q0);
            p0 = fmaf(h[0][2][e], c2[e], p0);
            q0 = fmaf(h[0][3][e], c3[e], q0);
            p1 = fmaf(h[1][0][e], c0[e], p1);
            q1 = fmaf(h[1][1][e], c1[e], q1);
            p1 = fmaf(h[1][2][e], c2[e], p1);
            q1 = fmaf(h[1][3][e], c3[e], q1);
        }
        float s0 = p0 + q0, s1 = p1 + q1;
        #pragma unroll
        for (int off = 32; off > 0; off >>= 1) {   // interleaved butterflies
            float u0 = __shfl_xor(s0, off);
            float u1 = __shfl_xor(s1, off);
            s0 += u0; s1 += u1;
        }
        if (mk.x != 0) {                            // wave-uniform
            if (s0 > m) {                           // deferred rescale (rare)
                float cc = __expf(m - s0);          // m=-inf first time -> 0
                l *= cc; a0 *= cc; a1 *= cc; a2 *= cc; a3 *= cc; m = s0;
            }
            float w = __expf(s0 - m); l += w;
            a0 += w * h[0][0]; a1 += w * h[0][1];
            a2 += w * h[0][2]; a3 += w * h[0][3];
        }
        if (mk.y != 0) {
            if (s1 > m) {
                float cc = __expf(m - s1);
                l *= cc; a0 *= cc; a1 *= cc; a2 *= cc; a3 *= cc; m = s1;
            }
            float w = __expf(s1 - m); l += w;
            a0 += w * h[1][0]; a1 += w * h[1][1];
            a2 += w * h[1][2]; a3 += w * h[1][3];
        }
    };

    loadG(hA, mA, 0);
    for (int g = 0; g < NG; g += 2) {
        if (g + 1 < NG) loadG(hB, mB, g + 1);
        computeG(hA, mA);
        if (g + 2 < NG) loadG(hA, mA, g + 2);
        if (g + 1 < NG) computeG(hB, mB);
    }

    // ---- cross-wave merge in LDS ----
    __shared__ float s_m[4];
    __shared__ float s_lf[4];
    __shared__ f32x4 s_acc[4][256];   // 16 KB
    __shared__ int   s_last;

    if (lane == 0) s_m[wave] = m;
    __syncthreads();
    float M = fmaxf(fmaxf(s_m[0], s_m[1]), fmaxf(s_m[2], s_m[3]));
    float f = (m == -INFINITY) ? 0.0f : __expf(m - M);
    if (lane == 0) s_lf[wave] = l * f;
    s_acc[wave][0 * 64 + lane] = a0 * f;
    s_acc[wave][1 * 64 + lane] = a1 * f;
    s_acc[wave][2 * 64 + lane] = a2 * f;
    s_acc[wave][3 * 64 + lane] = a3 * f;
    __syncthreads();

    f32x4 v0 = s_acc[0][tid], v1 = s_acc[1][tid], v2 = s_acc[2][tid], v3 = s_acc[3][tid];
    f32x4 r = (v0 + v1) + (v2 + v3);

    f32x4* accs4 = (f32x4*)(accs + (size_t)bi * D);
    accs4[tid] = r;
    if (tid == 0) {
        ms[bi] = M;
        ls[bi] = (s_lf[0] + s_lf[1]) + (s_lf[2] + s_lf[3]);
    }

    // ---- last-block-per-b combine (device-scope) ----
    __threadfence();               // release: partials visible device-wide
    __syncthreads();
    if (tid == 0) {
        int old = atomicAdd(&counters[b], 1);   // device-scope by default
        s_last = (old == blocksPerB - 1) ? 1 : 0;
    }
    __syncthreads();
    if (!s_last) return;
    __threadfence();               // acquire: see all other blocks' partials

    const float* mB2 = ms + (size_t)b * blocksPerB;
    const float* lB2 = ls + (size_t)b * blocksPerB;

    float M2 = -INFINITY;
    for (int c = 0; c < blocksPerB; ++c) M2 = fmaxf(M2, mB2[c]);
    float L2 = 0.0f;
    for (int c = 0; c < blocksPerB; ++c) {
        float mc = mB2[c];
        float fc = (mc == -INFINITY) ? 0.0f : __expf(mc - M2);
        L2 += lB2[c] * fc;
    }

    f32x4 racc = {0.f,0.f,0.f,0.f};
    const f32x4* allAccs4 = (const f32x4*)accs;
    for (int c = 0; c < blocksPerB; ++c) {
        float mc = mB2[c];
        float fc = (mc == -INFINITY) ? 0.0f : __expf(mc - M2);
        f32x4 v = allAccs4[((size_t)b * blocksPerB + c) * 256 + tid];
        racc.x = fmaf(v.x, fc, racc.x); racc.y = fmaf(v.y, fc, racc.y);
        racc.z = fmaf(v.z, fc, racc.z); racc.w = fmaf(v.w, fc, racc.w);
    }
    float inv = 1.0f / L2;
    ((f32x4*)out)[(size_t)b * 256 + tid] = racc * inv;
}

extern "C" void kernel_launch(void* const* d_in, const int* in_sizes, int n_in,
                              void* d_out, int out_size, void* d_ws, size_t ws_size,
                              hipStream_t stream)
{
    const float* hs   = (const float*)d_in[0];
    const int*   mask = (const int*)d_in[1];
    const float* ctx  = (const float*)d_in[2];

    const int D = 1024;
    int B = out_size / D;          // 16
    int T = in_sizes[1] / B;       // 4096

    // chunking: 64 chunks/b -> 1024 blocks (4/CU); shrink if ws too small.
    // tokensPerWave = T/(4*blocksPerB) is even for all reachable configs.
    int blocksPerB = 64;
    while (blocksPerB > 1 &&
           ((T % (4 * blocksPerB)) != 0 ||
            256 + (size_t)B * blocksPerB * (size_t)(D + 2) * sizeof(float) > ws_size))
        blocksPerB >>= 1;
    int tokensPerWave = T / (4 * blocksPerB);
    int numP = B * blocksPerB;

    // ws layout: [counters: B ints, padded to 256 B][accs][ms][ls]
    int*   counters = (int*)d_ws;
    float* accs     = (float*)((char*)d_ws + 256);
    float* ms       = accs + (size_t)numP * D;
    float* ls       = ms + numP;

    (void)hipMemsetAsync(counters, 0, 256, stream);   // ws is re-poisoned 0xAA each call
    ap_fused<<<numP, 256, 0, stream>>>(hs, mask, ctx, accs, ms, ls,
                                       counters, (float*)d_out,
                                       T, blocksPerB, tokensPerWave);
}

// Round 12
// 401.808 us; speedup vs baseline: 1.4804x; 1.4804x over previous
//
#include <hip/hip_runtime.h>
#include <math.h>

// AttentionPool: scores = einsum("btd,d->bt"), masked softmax over T,
// pooled = einsum("bt,btd->bd").  B=16, T=4096, D=1024, f32.
//
// Two kernels (fusion via threadfence/atomic REGRESSED: device-scope fences
// per block on non-coherent XCD L2s; kernel boundary is free ordering).
// Kernel 1 (ap_partial): 2048 blocks x 256 thr (4 waves). Wave owns 8 tokens,
//   processed in 4-token batches: 16 independent dwordx4 loads issued first,
//   4 independent dot chains, 4-way interleaved butterfly reduce, then
//   online-softmax accumulate (deferred rescale). Lanes split D: lane owns
//   d = j*256 + lane*4, j=0..3. Partial (m, l, acc[1024]) per block -> d_ws.
// Kernel 2 (ap_combine): per-b rescale + normalize + write out.

typedef float f32x4 __attribute__((ext_vector_type(4)));

__global__ __launch_bounds__(256) void ap_partial(
    const float* __restrict__ hs, const int* __restrict__ mask,
    const float* __restrict__ ctx,
    float* __restrict__ accs, float* __restrict__ ms, float* __restrict__ ls,
    int T, int blocksPerB, int tokensPerWave)
{
    const int D = 1024;            // layout assumption: D == 1024 (4*64*4)
    int bi    = blockIdx.x;
    int b     = bi / blocksPerB;
    int chunk = bi - b * blocksPerB;
    int wave  = threadIdx.x >> 6;
    int lane  = threadIdx.x & 63;
    int tid   = threadIdx.x;

    int t0 = chunk * (tokensPerWave * 4) + wave * tokensPerWave;

    const f32x4* ctx4 = (const f32x4*)ctx;
    f32x4 c0 = ctx4[0 * 64 + lane];
    f32x4 c1 = ctx4[1 * 64 + lane];
    f32x4 c2 = ctx4[2 * 64 + lane];
    f32x4 c3 = ctx4[3 * 64 + lane];

    f32x4 a0 = {0.f,0.f,0.f,0.f}, a1 = {0.f,0.f,0.f,0.f};
    f32x4 a2 = {0.f,0.f,0.f,0.f}, a3 = {0.f,0.f,0.f,0.f};
    float m = -INFINITY, l = 0.0f;

    const f32x4* hp = (const f32x4*)hs + ((size_t)b * T + t0) * (D / 4);
    const int*   mp = mask + (size_t)b * T + t0;

    // tokensPerWave is a multiple of 4 for all reachable configs (T/(4*bpB)).
    for (int g = 0; g < tokensPerWave; g += 4) {
        // ---- issue all 16 loads (4 tokens x 4 dwordx4) before any consumer ----
        f32x4 h[4][4];                       // [token][j] — all indices static
        #pragma unroll
        for (int t = 0; t < 4; ++t) {
            const f32x4* row = hp + (size_t)(g + t) * (D / 4);
            #pragma unroll
            for (int j = 0; j < 4; ++j) h[t][j] = row[j * 64 + lane];
        }
        int4 mk4 = *(const int4*)(mp + g);   // 16B-aligned: g,t0 multiples of 4

        // ---- 4 independent dot chains ----
        float s0, s1, s2, s3;
        {
            float p, q;
            p = 0.f; q = 0.f;
            #pragma unroll
            for (int e = 0; e < 4; ++e) {
                p = fmaf(h[0][0][e], c0[e], p); q = fmaf(h[0][1][e], c1[e], q);
                p = fmaf(h[0][2][e], c2[e], p); q = fmaf(h[0][3][e], c3[e], q);
            }
            s0 = p + q;
            p = 0.f; q = 0.f;
            #pragma unroll
            for (int e = 0; e < 4; ++e) {
                p = fmaf(h[1][0][e], c0[e], p); q = fmaf(h[1][1][e], c1[e], q);
                p = fmaf(h[1][2][e], c2[e], p); q = fmaf(h[1][3][e], c3[e], q);
            }
            s1 = p + q;
            p = 0.f; q = 0.f;
            #pragma unroll
            for (int e = 0; e < 4; ++e) {
                p = fmaf(h[2][0][e], c0[e], p); q = fmaf(h[2][1][e], c1[e], q);
                p = fmaf(h[2][2][e], c2[e], p); q = fmaf(h[2][3][e], c3[e], q);
            }
            s2 = p + q;
            p = 0.f; q = 0.f;
            #pragma unroll
            for (int e = 0; e < 4; ++e) {
                p = fmaf(h[3][0][e], c0[e], p); q = fmaf(h[3][1][e], c1[e], q);
                p = fmaf(h[3][2][e], c2[e], p); q = fmaf(h[3][3][e], c3[e], q);
            }
            s3 = p + q;
        }

        // ---- 4-way interleaved butterfly reduce (amortize shuffle latency) ----
        #pragma unroll
        for (int off = 32; off > 0; off >>= 1) {
            float u0 = __shfl_xor(s0, off);
            float u1 = __shfl_xor(s1, off);
            float u2 = __shfl_xor(s2, off);
            float u3 = __shfl_xor(s3, off);
            s0 += u0; s1 += u1; s2 += u2; s3 += u3;
        }

        // ---- online-softmax accumulate (wave-uniform branches) ----
        if (mk4.x != 0) {
            if (s0 > m) { float cc = __expf(m - s0); l *= cc; a0 *= cc; a1 *= cc; a2 *= cc; a3 *= cc; m = s0; }
            float w = __expf(s0 - m); l += w;
            a0 += w * h[0][0]; a1 += w * h[0][1]; a2 += w * h[0][2]; a3 += w * h[0][3];
        }
        if (mk4.y != 0) {
            if (s1 > m) { float cc = __expf(m - s1); l *= cc; a0 *= cc; a1 *= cc; a2 *= cc; a3 *= cc; m = s1; }
            float w = __expf(s1 - m); l += w;
            a0 += w * h[1][0]; a1 += w * h[1][1]; a2 += w * h[1][2]; a3 += w * h[1][3];
        }
        if (mk4.z != 0) {
            if (s2 > m) { float cc = __expf(m - s2); l *= cc; a0 *= cc; a1 *= cc; a2 *= cc; a3 *= cc; m = s2; }
            float w = __expf(s2 - m); l += w;
            a0 += w * h[2][0]; a1 += w * h[2][1]; a2 += w * h[2][2]; a3 += w * h[2][3];
        }
        if (mk4.w != 0) {
            if (s3 > m) { float cc = __expf(m - s3); l *= cc; a0 *= cc; a1 *= cc; a2 *= cc; a3 *= cc; m = s3; }
            float w = __expf(s3 - m); l += w;
            a0 += w * h[3][0]; a1 += w * h[3][1]; a2 += w * h[3][2]; a3 += w * h[3][3];
        }
    }

    // ---- cross-wave merge in LDS ----
    __shared__ float s_m[4];
    __shared__ float s_lf[4];
    __shared__ f32x4 s_acc[4][256];   // 16 KB

    if (lane == 0) s_m[wave] = m;
    __syncthreads();
    float M = fmaxf(fmaxf(s_m[0], s_m[1]), fmaxf(s_m[2], s_m[3]));
    float f = (m == -INFINITY) ? 0.0f : __expf(m - M);
    if (lane == 0) s_lf[wave] = l * f;
    s_acc[wave][0 * 64 + lane] = a0 * f;
    s_acc[wave][1 * 64 + lane] = a1 * f;
    s_acc[wave][2 * 64 + lane] = a2 * f;
    s_acc[wave][3 * 64 + lane] = a3 * f;
    __syncthreads();

    f32x4 v0 = s_acc[0][tid], v1 = s_acc[1][tid], v2 = s_acc[2][tid], v3 = s_acc[3][tid];
    f32x4 r = (v0 + v1) + (v2 + v3);

    f32x4* accs4 = (f32x4*)(accs + (size_t)bi * D);
    accs4[tid] = r;
    if (tid == 0) {
        ms[bi] = M;
        ls[bi] = (s_lf[0] + s_lf[1]) + (s_lf[2] + s_lf[3]);
    }
}

__global__ __launch_bounds__(256) void ap_combine(
    const float* __restrict__ accs, const float* __restrict__ ms,
    const float* __restrict__ ls, float* __restrict__ out, int numChunks)
{
    int b   = blockIdx.x;
    int tid = threadIdx.x;
    const float* mB = ms + (size_t)b * numChunks;
    const float* lB = ls + (size_t)b * numChunks;

    float M = -INFINITY;
    for (int c = 0; c < numChunks; ++c) M = fmaxf(M, mB[c]);
    float L = 0.0f;
    for (int c = 0; c < numChunks; ++c) {
        float mc = mB[c];
        float fc = (mc == -INFINITY) ? 0.0f : __expf(mc - M);
        L += lB[c] * fc;
    }

    f32x4 racc = {0.f,0.f,0.f,0.f};
    const f32x4* accs4 = (const f32x4*)accs;
    for (int c = 0; c < numChunks; ++c) {
        float mc = mB[c];
        float fc = (mc == -INFINITY) ? 0.0f : __expf(mc - M);
        f32x4 v = accs4[((size_t)b * numChunks + c) * 256 + tid];
        racc.x = fmaf(v.x, fc, racc.x); racc.y = fmaf(v.y, fc, racc.y);
        racc.z = fmaf(v.z, fc, racc.z); racc.w = fmaf(v.w, fc, racc.w);
    }
    float inv = 1.0f / L;
    ((f32x4*)out)[(size_t)b * 256 + tid] = racc * inv;
}

extern "C" void kernel_launch(void* const* d_in, const int* in_sizes, int n_in,
                              void* d_out, int out_size, void* d_ws, size_t ws_size,
                              hipStream_t stream)
{
    const float* hs   = (const float*)d_in[0];
    const int*   mask = (const int*)d_in[1];
    const float* ctx  = (const float*)d_in[2];

    const int D = 1024;
    int B = out_size / D;          // 16
    int T = in_sizes[1] / B;       // 4096

    // chunking: 128 chunks/b -> 2048 blocks (8/CU), 8 tokens/wave (2 batches);
    // shrink if ws too small or T not divisible. tokensPerWave stays a
    // multiple of 4 for all reachable configs.
    int blocksPerB = 128;
    while (blocksPerB > 1 &&
           ((T % (16 * blocksPerB)) != 0 ||
            (size_t)B * blocksPerB * (size_t)(D + 2) * sizeof(float) > ws_size))
        blocksPerB >>= 1;
    int tokensPerWave = T / (4 * blocksPerB);
    int numP = B * blocksPerB;

    float* accs = (float*)d_ws;
    float* ms   = accs + (size_t)numP * D;
    float* ls   = ms + numP;

    ap_partial<<<numP, 256, 0, stream>>>(hs, mask, ctx, accs, ms, ls,
                                         T, blocksPerB, tokensPerWave);
    ap_combine<<<B, 256, 0, stream>>>(accs, ms, ls, (float*)d_out, blocksPerB);
}

// Round 13
// 376.156 us; speedup vs baseline: 1.5813x; 1.0682x over previous
//
#include <hip/hip_runtime.h>
#include <math.h>

// AttentionPool: scores = einsum("btd,d->bt"), masked softmax over T,
// pooled = einsum("bt,btd->bd").  B=16, T=4096, D=1024, f32.
//
// Round-12 post-mortem: register-convoy structure (issue batch, vmcnt(0),
// consume) plateaus at ~1.7 TB/s regardless of batch width/occupancy.
// This version: per-wave 4-slot LDS ring fed by global_load_lds (DMA, no
// dest VGPR -> compiler cannot sink it) with counted vmcnt waits:
//   stage(t+3); s_waitcnt vmcnt(12); compute(t from LDS)
// Loads never drain to zero -> continuous streaming like a copy kernel.
// 512 blocks x 256 thr (4 waves), 64KB LDS ring + aliased merge buffer:
// exactly 2 blocks/CU, all blocks resident.

typedef float f32x4 __attribute__((ext_vector_type(4)));

using as1_void = __attribute__((address_space(1))) void;
using as3_void = __attribute__((address_space(3))) void;

__device__ __forceinline__ void gload_lds16(const void* g, void* l) {
    __builtin_amdgcn_global_load_lds((as1_void*)(void*)(const_cast<void*>(g)),
                                     (as3_void*)(l), 16, 0, 0);
}

__global__ __launch_bounds__(256) void ap_partial(
    const float* __restrict__ hs, const int* __restrict__ mask,
    const float* __restrict__ ctx,
    float* __restrict__ accs, float* __restrict__ ms, float* __restrict__ ls,
    int T, int blocksPerB, int tokensPerWave)
{
    const int D = 1024;            // layout assumption: D == 1024
    int bi    = blockIdx.x;
    int b     = bi / blocksPerB;
    int chunk = bi - b * blocksPerB;
    int wave  = threadIdx.x >> 6;
    int lane  = threadIdx.x & 63;
    int tid   = threadIdx.x;
    int TW    = tokensPerWave;     // 32 for the bench shape; 4 <= TW <= 64

    int t0 = chunk * (TW * 4) + wave * TW;

    __shared__ char  smem[65536];  // [wave][slot][4KB] ring; aliased as merge buf
    __shared__ float s_m[4];
    __shared__ float s_lf[4];

    const f32x4* ctx4 = (const f32x4*)ctx;
    f32x4 c0 = ctx4[0 * 64 + lane];
    f32x4 c1 = ctx4[1 * 64 + lane];
    f32x4 c2 = ctx4[2 * 64 + lane];
    f32x4 c3 = ctx4[3 * 64 + lane];

    const float* hp = hs + ((size_t)b * T + t0) * D;
    const int*   mp = mask + (size_t)b * T + t0;
    int mymask = mp[lane < TW ? lane : 0];   // lane i holds mask of token i

    f32x4 a0 = {0.f,0.f,0.f,0.f}, a1 = {0.f,0.f,0.f,0.f};
    f32x4 a2 = {0.f,0.f,0.f,0.f}, a3 = {0.f,0.f,0.f,0.f};
    float m = -INFINITY, l = 0.0f;

    char* ringbase = smem + wave * 16384;

    auto stage = [&](int t) {
        // wave-uniform LDS base + lane*16 is the HW-defined dest layout;
        // per-lane global src matches it exactly (lane's 16B of the row).
        const float* rp = hp + (size_t)t * D + lane * 4;
        char* lb = ringbase + (t & 3) * 4096;
        gload_lds16(rp,       lb);
        gload_lds16(rp + 256, lb + 1024);
        gload_lds16(rp + 512, lb + 2048);
        gload_lds16(rp + 768, lb + 3072);
    };

    auto compute = [&](int t) {
        const f32x4* sp = (const f32x4*)(ringbase + (t & 3) * 4096);
        f32x4 h0 = sp[0 * 64 + lane];
        f32x4 h1 = sp[1 * 64 + lane];
        f32x4 h2 = sp[2 * 64 + lane];
        f32x4 h3 = sp[3 * 64 + lane];
        float p = 0.f, q = 0.f;
        #pragma unroll
        for (int e = 0; e < 4; ++e) {
            p = fmaf(h0[e], c0[e], p); q = fmaf(h1[e], c1[e], q);
            p = fmaf(h2[e], c2[e], p); q = fmaf(h3[e], c3[e], q);
        }
        float s = p + q;
        #pragma unroll
        for (int off = 32; off > 0; off >>= 1) s += __shfl_xor(s, off);
        int mk = __shfl(mymask, t);            // lane t holds mp[t]
        if (mk != 0) {                         // wave-uniform
            if (s > m) {                       // deferred rescale (rare)
                float cc = __expf(m - s);      // m=-inf first time -> 0
                l *= cc; a0 *= cc; a1 *= cc; a2 *= cc; a3 *= cc; m = s;
            }
            float w = __expf(s - m); l += w;
            a0 += w * h0; a1 += w * h1; a2 += w * h2; a3 += w * h3;
        }
    };

    // drain mask/ctx loads so pipeline vmcnt bookkeeping starts clean
    asm volatile("s_waitcnt vmcnt(0)" ::: "memory");

    stage(0); stage(1); stage(2);              // prologue: 12 loads in flight
    int t = 0;
    for (; t < TW - 3; ++t) {
        stage(t + 3);                          // 16 in flight
        asm volatile("s_waitcnt vmcnt(12)" ::: "memory");  // token t resolved
        compute(t);
    }
    asm volatile("s_waitcnt vmcnt(8)" ::: "memory");
    compute(t); ++t;
    asm volatile("s_waitcnt vmcnt(4)" ::: "memory");
    compute(t); ++t;
    asm volatile("s_waitcnt vmcnt(0)" ::: "memory");
    compute(t);

    // ---- cross-wave merge (reuse ring LDS after barrier) ----
    __syncthreads();                           // all ring reads done
    f32x4* s_acc = (f32x4*)smem;               // [wave*256 + idx], 16KB

    if (lane == 0) s_m[wave] = m;
    __syncthreads();
    float M = fmaxf(fmaxf(s_m[0], s_m[1]), fmaxf(s_m[2], s_m[3]));
    float f = (m == -INFINITY) ? 0.0f : __expf(m - M);
    if (lane == 0) s_lf[wave] = l * f;
    s_acc[wave * 256 + 0 * 64 + lane] = a0 * f;
    s_acc[wave * 256 + 1 * 64 + lane] = a1 * f;
    s_acc[wave * 256 + 2 * 64 + lane] = a2 * f;
    s_acc[wave * 256 + 3 * 64 + lane] = a3 * f;
    __syncthreads();

    f32x4 v0 = s_acc[0 * 256 + tid], v1 = s_acc[1 * 256 + tid];
    f32x4 v2 = s_acc[2 * 256 + tid], v3 = s_acc[3 * 256 + tid];
    f32x4 r = (v0 + v1) + (v2 + v3);

    f32x4* accs4 = (f32x4*)(accs + (size_t)bi * D);
    accs4[tid] = r;
    if (tid == 0) {
        ms[bi] = M;
        ls[bi] = (s_lf[0] + s_lf[1]) + (s_lf[2] + s_lf[3]);
    }
}

__global__ __launch_bounds__(256) void ap_combine(
    const float* __restrict__ accs, const float* __restrict__ ms,
    const float* __restrict__ ls, float* __restrict__ out, int numChunks)
{
    int b   = blockIdx.x;
    int tid = threadIdx.x;
    const float* mB = ms + (size_t)b * numChunks;
    const float* lB = ls + (size_t)b * numChunks;

    float M = -INFINITY;
    for (int c = 0; c < numChunks; ++c) M = fmaxf(M, mB[c]);
    float L = 0.0f;
    for (int c = 0; c < numChunks; ++c) {
        float mc = mB[c];
        float fc = (mc == -INFINITY) ? 0.0f : __expf(mc - M);
        L += lB[c] * fc;
    }

    f32x4 racc = {0.f,0.f,0.f,0.f};
    const f32x4* accs4 = (const f32x4*)accs;
    for (int c = 0; c < numChunks; ++c) {
        float mc = mB[c];
        float fc = (mc == -INFINITY) ? 0.0f : __expf(mc - M);
        f32x4 v = accs4[((size_t)b * numChunks + c) * 256 + tid];
        racc.x = fmaf(v.x, fc, racc.x); racc.y = fmaf(v.y, fc, racc.y);
        racc.z = fmaf(v.z, fc, racc.z); racc.w = fmaf(v.w, fc, racc.w);
    }
    float inv = 1.0f / L;
    ((f32x4*)out)[(size_t)b * 256 + tid] = racc * inv;
}

extern "C" void kernel_launch(void* const* d_in, const int* in_sizes, int n_in,
                              void* d_out, int out_size, void* d_ws, size_t ws_size,
                              hipStream_t stream)
{
    const float* hs   = (const float*)d_in[0];
    const int*   mask = (const int*)d_in[1];
    const float* ctx  = (const float*)d_in[2];

    const int D = 1024;
    int B = out_size / D;          // 16
    int T = in_sizes[1] / B;       // 4096

    // pick blocksPerB: need T % (4*p) == 0, TW = T/(4p) in [4,64], ws fits.
    // For the bench shape p=32 -> 512 blocks (exactly 2/CU), TW=32.
    const int cand[5] = {32, 64, 16, 128, 8};
    int blocksPerB = 0;
    for (int i = 0; i < 5; ++i) {
        int p  = cand[i];
        if (T % (4 * p) != 0) continue;
        int tw = T / (4 * p);
        if (tw < 4 || tw > 64) continue;
        if ((size_t)B * p * (size_t)(D + 2) * sizeof(float) > ws_size) continue;
        blocksPerB = p; break;
    }
    if (blocksPerB == 0) blocksPerB = T / 128;   // fallback (unreached for bench)
    int tokensPerWave = T / (4 * blocksPerB);
    int numP = B * blocksPerB;

    float* accs = (float*)d_ws;
    float* ms   = accs + (size_t)numP * D;
    float* ls   = ms + numP;

    ap_partial<<<numP, 256, 0, stream>>>(hs, mask, ctx, accs, ms, ls,
                                         T, blocksPerB, tokensPerWave);
    ap_combine<<<B, 256, 0, stream>>>(accs, ms, ls, (float*)d_out, blocksPerB);
}